// Round 6
// baseline (205.537 us; speedup 1.0000x reference)
//
#include <hip/hip_runtime.h>

// Problem constants (match reference)
#define B_ 4
#define N_ 16384
#define M_ 128
#define C_ 128
#define S_ 512
#define ROW_ 131           // 3 + C floats per pooled row
#define NCHUNK_ 256        // 64-point chunks per box (N_/64)
#define TILE_ 128          // unique rows staged in LDS per box
#define LSTR_ 136          // swizzled LDS row stride (floats)

typedef float f4_t __attribute__((ext_vector_type(4)));

// Swizzled LDS address: for a fixed element-within-float4 slot, consecutive
// lanes (col += 4) land on consecutive banks -> conflict-free ds_read_b32.
// Injective for col in [0,131): (col&3)*34 + (col>>2) <= 3*34+32 = 134 < 136.
__device__ __forceinline__ int swz(int j, int col) {
    return j * LSTR_ + (col & 3) * 34 + (col >> 2);
}

// ---------------------------------------------------------------------------
// Fully fused: one 256-thread block per box.
//   1) mask phase: each wave ballots 64 contiguous 64-point chunks straight
//      into LDS (points are L2-resident: 786 KB total, read 100 MB aggregate)
//   2) Hillis–Steele scan of 256 chunk counts
//   3) expand first min(cnt,S) ordered in-box indices
//   4) jtab[s] = s % cnt (modulo hoisted off the stream path)
//   5) stage up to TILE_ unique rows in swizzled LDS (float4 global reads)
//   6) stream 512x131 floats as NT float4 pure write stream (~22 us floor)
// LDS: srow 69.6K + masks 2K + sc 1K + s_idx 2K + jtab 2K ~= 77K -> 2 blk/CU.
// ---------------------------------------------------------------------------
__global__ __launch_bounds__(256) void roipool_fused_kernel(
    const float* __restrict__ points,        // (B, N, 3)
    const float* __restrict__ feats,         // (B, N, C)
    const float* __restrict__ boxes,         // (B*M, 7)
    float* __restrict__ out,                 // (B, M, S, 131)
    float* __restrict__ flags_out)           // (B*M,)
{
    const int bm   = blockIdx.x;
    const int b    = bm >> 7;
    const int tid  = threadIdx.x;
    const int w    = tid >> 6;
    const int lane = tid & 63;

    __shared__ unsigned long long s_mask[NCHUNK_];
    __shared__ int   sc[NCHUNK_];
    __shared__ int   s_idx[S_];
    __shared__ int   jtab[S_ + 1];           // +1: streaming reads jtab[s0+1]
    __shared__ float srow[TILE_ * LSTR_];

    // --- box parameters (fp32 reference semantics: no FMA contraction;
    //     trig via double -> correctly-rounded fp32) ---
    const float* bx = boxes + bm * 7;
    const float cx = bx[0], cy = bx[1], czb = bx[2];
    const float dx = bx[3], dy = bx[4], dzv = bx[5], rz = bx[6];
    const float cz   = __fadd_rn(czb, __fmul_rn(0.5f, dzv));
    const float cosa = (float)cos(-(double)rz);
    const float sina = (float)sin(-(double)rz);
    const float hdx = 0.5f * dx, hdy = 0.5f * dy, hdz = 0.5f * dzv;

    // --- 1) mask phase: wave w ballots chunks [w*64, (w+1)*64) ---
    const float* pb = points + (size_t)b * N_ * 3;
    #pragma unroll 4
    for (int k = 0; k < 64; ++k) {
        const int chunk = w * 64 + k;
        const int i = chunk * 64 + lane;
        const float x = pb[i*3+0], y = pb[i*3+1], z = pb[i*3+2];
        const float sx = __fsub_rn(x, cx);
        const float sy = __fsub_rn(y, cy);
        const float lx = __fsub_rn(__fmul_rn(sx, cosa), __fmul_rn(sy, sina));
        const float ly = __fadd_rn(__fmul_rn(sx, sina), __fmul_rn(sy, cosa));
        const bool pred = (fabsf(__fsub_rn(z, cz)) <= hdz) &&
                          (lx > -hdx) && (lx < hdx) &&
                          (ly > -hdy) && (ly < hdy);
        const unsigned long long m = __ballot(pred);
        if (lane == 0) {
            s_mask[chunk] = m;
            sc[chunk]     = __popcll(m);
        }
    }
    __syncthreads();

    // --- 2) scan chunk counts (Hillis–Steele, 8 rounds) ---
    const int c = sc[tid];
    for (int off = 1; off < NCHUNK_; off <<= 1) {
        const int v = (tid >= off) ? sc[tid - off] : 0;
        __syncthreads();
        sc[tid] += v;
        __syncthreads();
    }
    const int total = sc[NCHUNK_ - 1];
    const int P = sc[tid] - c;               // exclusive prefix (ordered)

    // --- 3) expand ordered in-box indices ---
    if (c > 0 && P < S_) {
        unsigned long long m = s_mask[tid];
        int pos = P;
        while (m && pos < S_) {
            const int bit = __ffsll((unsigned long long)m) - 1;
            m &= m - 1;
            s_idx[pos++] = tid * 64 + bit;
        }
    }
    __syncthreads();

    // --- 4) wrap-around table (full cnt as denominator when cnt<=S;
    //         when cnt>S, s % min(cnt,S) == s for s<S: identical result) ---
    const int cnt_eff = total < S_ ? total : S_;
    const int denom   = cnt_eff > 0 ? cnt_eff : 1;
    for (int s = tid; s <= S_; s += 256) jtab[s] = (s < S_) ? (s % denom) : 0;

    // --- 5) stage unique rows into swizzled LDS ---
    const int T = cnt_eff < TILE_ ? cnt_eff : TILE_;
    if (total == 0) {
        if (tid < LSTR_) srow[tid] = 0.0f;   // row 0 zeros (j is always 0)
    } else {
        const int nf4 = T * 32;              // 32 float4s of features per row
        for (int t = tid; t < nf4; t += 256) {
            const int u = t >> 5, q = t & 31;
            const size_t pbase = (size_t)b * N_ + (unsigned)s_idx[u];
            const f4_t v = *(const f4_t*)(feats + pbase * C_ + q * 4);
            #pragma unroll
            for (int jj = 0; jj < 4; ++jj)
                srow[swz(u, 3 + 4 * q + jj)] = v[jj];   // <=2-way: free
        }
        for (int t = tid; t < T * 3; t += 256) {
            const int u = t / 3, k = t - u * 3;
            const size_t pbase = (size_t)b * N_ + (unsigned)s_idx[u];
            srow[swz(u, k)] = points[pbase * 3 + k];
        }
    }
    __syncthreads();

    // --- 6) stream output: 512*131 = 67072 floats = 16768 aligned float4s ---
    float* ob = out + (size_t)bm * (S_ * ROW_);
    for (int f = tid; f < (S_ * ROW_) / 4; f += 256) {
        const int e = 4 * f;
        const unsigned s0 = (unsigned)e / (unsigned)ROW_;  // magic-mul
        const int col0 = e - (int)s0 * ROW_;
        const int ja = jtab[s0], jb = jtab[s0 + 1];
        f4_t v;
        if ((ja < TILE_) & (jb < TILE_)) {   // common case: both rows staged
            #pragma unroll
            for (int jj = 0; jj < 4; ++jj) {
                int col = col0 + jj;
                const bool cross = col >= ROW_;
                col = cross ? col - ROW_ : col;
                const int j = cross ? jb : ja;
                v[jj] = srow[swz(j, col)];   // stride-1 banks: conflict-free
            }
        } else {                             // rare: cnt_eff > TILE_
            #pragma unroll
            for (int jj = 0; jj < 4; ++jj) {
                int col = col0 + jj;
                unsigned s = s0;
                if (col >= ROW_) { col -= ROW_; ++s; }
                const int j = jtab[s];
                float val;
                if (j < TILE_) {
                    val = srow[swz(j, col)];
                } else {
                    const size_t pbase = (size_t)b * N_ + (unsigned)s_idx[j];
                    val = (col < 3) ? points[pbase * 3 + col]
                                    : feats[pbase * C_ + (col - 3)];
                }
                v[jj] = val;
            }
        }
        __builtin_nontemporal_store(v, (f4_t*)(ob + e));
    }
    if (tid == 0) flags_out[bm] = (total == 0) ? 1.0f : 0.0f;
}

extern "C" void kernel_launch(void* const* d_in, const int* in_sizes, int n_in,
                              void* d_out, int out_size, void* d_ws, size_t ws_size,
                              hipStream_t stream) {
    const float* points = (const float*)d_in[0];   // (B, N, 3)
    const float* feats  = (const float*)d_in[1];   // (B, N, C)
    const float* boxes  = (const float*)d_in[2];   // (B, M, 7)
    float* out = (float*)d_out;
    float* flags = out + (size_t)B_ * M_ * S_ * ROW_;

    // Single fused kernel: one block per box (d_ws no longer needed)
    roipool_fused_kernel<<<B_ * M_, 256, 0, stream>>>(
        points, feats, boxes, out, flags);
}

// Round 7
// 184.401 us; speedup vs baseline: 1.1146x; 1.1146x over previous
//
#include <hip/hip_runtime.h>

// Problem constants (match reference)
#define B_ 4
#define N_ 16384
#define M_ 128
#define C_ 128
#define S_ 512
#define ROW_ 131           // 3 + C floats per pooled row
#define NCHUNK_ 256        // 64-point chunks per box (N_/64)
#define TILE_ 128          // unique rows staged in LDS per box
#define LSTR_ 136          // swizzled LDS row stride (floats)
#define KBOX_ 4            // boxes per wave in mask kernel

typedef float f4_t __attribute__((ext_vector_type(4)));

// Swizzled LDS address: for a fixed element-within-float4 slot, consecutive
// lanes (col += 4) land on consecutive banks -> conflict-free ds_read_b32.
// Injective for col in [0,131): (col&3)*34 + (col>>2) <= 3*34+32 = 134 < 136.
__device__ __forceinline__ int swz(int j, int col) {
    return j * LSTR_ + (col & 3) * 34 + (col >> 2);
}

// ---------------------------------------------------------------------------
// Phase A: per-(box, chunk) in-box bitmask via wave ballot.
// One wave holds 16 chunks (1024 points, 48 VGPRs) and tests them against
// KBOX_ consecutive boxes (same batch since 128 % KBOX_ == 0) — points are
// read once per 4 boxes. 2048 waves total → full-occupancy, latency-friendly.
// (R6 lesson: fusing this into the per-box block forfeits the 4× reuse and
// runs it at 8 waves/CU → +18 µs. Keep it split.)
// ---------------------------------------------------------------------------
__global__ __launch_bounds__(256) void mask_kernel(
    const float* __restrict__ points,        // (B, N, 3)
    const float* __restrict__ boxes,         // (B*M, 7)
    unsigned long long* __restrict__ masks,  // (B*M, NCHUNK_)
    int* __restrict__ cnts)                  // (B*M, NCHUNK_)
{
    const int gwave = blockIdx.x * 4 + (threadIdx.x >> 6);
    const int lane  = threadIdx.x & 63;
    const int grp   = gwave >> 4;            // box-group [0, B*M/KBOX_)
    const int seg   = gwave & 15;            // 16 chunks per segment
    const int bm0   = grp * KBOX_;
    const int b     = bm0 >> 7;              // batch (shared by the 4 boxes)

    const float* pb = points + (size_t)b * N_ * 3;
    float px[16], py[16], pz[16];
    #pragma unroll
    for (int k = 0; k < 16; ++k) {
        const int i = (seg * 16 + k) * 64 + lane;
        px[k] = pb[i*3+0]; py[k] = pb[i*3+1]; pz[k] = pb[i*3+2];
    }

    for (int kb = 0; kb < KBOX_; ++kb) {
        const int bm = bm0 + kb;
        const float* bx = boxes + bm * 7;
        const float cx = bx[0], cy = bx[1], czb = bx[2];
        const float dx = bx[3], dy = bx[4], dzv = bx[5], rz = bx[6];
        // fp32 reference semantics: no FMA contraction; trig via double->fp32
        const float cz   = __fadd_rn(czb, __fmul_rn(0.5f, dzv));
        const float cosa = (float)cos(-(double)rz);
        const float sina = (float)sin(-(double)rz);
        const float hdx = 0.5f * dx, hdy = 0.5f * dy, hdz = 0.5f * dzv;

        #pragma unroll
        for (int k = 0; k < 16; ++k) {
            const float sx = __fsub_rn(px[k], cx);
            const float sy = __fsub_rn(py[k], cy);
            const float lx = __fsub_rn(__fmul_rn(sx, cosa), __fmul_rn(sy, sina));
            const float ly = __fadd_rn(__fmul_rn(sx, sina), __fmul_rn(sy, cosa));
            const bool pred = (fabsf(__fsub_rn(pz[k], cz)) <= hdz) &&
                              (lx > -hdx) && (lx < hdx) &&
                              (ly > -hdy) && (ly < hdy);
            const unsigned long long m = __ballot(pred);
            if (lane == 0) {
                const int chunk = seg * 16 + k;
                masks[(size_t)bm * NCHUNK_ + chunk] = m;
                cnts [(size_t)bm * NCHUNK_ + chunk] = __popcll(m);
            }
        }
    }
}

// ---------------------------------------------------------------------------
// Fused resolve + pool: one block per box.
// shuffle-scan counts (1 barrier) -> expand first min(cnt,S) ordered indices
// -> jtab[s]=s%cnt -> stage up to TILE_ rows in swizzled LDS -> stream
// 512x131 floats as NT float4 pure write stream (~22 us HBM floor).
// ---------------------------------------------------------------------------
__global__ __launch_bounds__(256) void pool_kernel(
    const float* __restrict__ points,        // (B, N, 3)
    const float* __restrict__ feats,         // (B, N, C)
    const unsigned long long* __restrict__ masks,
    const int* __restrict__ cnts,
    float* __restrict__ out,                 // (B, M, S, 131)
    float* __restrict__ flags_out)           // (B*M,)
{
    const int bm   = blockIdx.x;
    const int b    = bm >> 7;
    const int tid  = threadIdx.x;
    const int w    = tid >> 6;
    const int lane = tid & 63;

    __shared__ int   s_wsum[4];
    __shared__ int   s_idx[S_];
    __shared__ int   jtab[S_ + 1];           // +1: streaming reads jtab[s0+1]
    __shared__ float srow[TILE_ * LSTR_];

    // --- scan chunk counts: wave shuffle-scan + 1 barrier ---
    const int c = cnts[(size_t)bm * NCHUNK_ + tid];
    int incl = c;
    #pragma unroll
    for (int d = 1; d < 64; d <<= 1) {
        const int t = __shfl_up(incl, d, 64);
        if (lane >= d) incl += t;
    }
    if (lane == 63) s_wsum[w] = incl;
    __syncthreads();
    const int w0 = s_wsum[0], w1 = s_wsum[1], w2 = s_wsum[2], w3 = s_wsum[3];
    const int woff  = (w > 0 ? w0 : 0) + (w > 1 ? w1 : 0) + (w > 2 ? w2 : 0);
    const int total = w0 + w1 + w2 + w3;
    const int P = incl - c + woff;           // exclusive prefix (ordered)

    // --- expand ordered in-box indices ---
    if (c > 0 && P < S_) {
        unsigned long long m = masks[(size_t)bm * NCHUNK_ + tid];
        int pos = P;
        while (m && pos < S_) {
            const int bit = __ffsll((unsigned long long)m) - 1;
            m &= m - 1;
            s_idx[pos++] = tid * 64 + bit;
        }
    }
    __syncthreads();

    // --- wrap-around table ---
    const int cnt_eff = total < S_ ? total : S_;
    const int denom   = cnt_eff > 0 ? cnt_eff : 1;
    for (int s = tid; s <= S_; s += 256) jtab[s] = (s < S_) ? (s % denom) : 0;

    // --- stage unique rows into swizzled LDS ---
    const int T = cnt_eff < TILE_ ? cnt_eff : TILE_;
    if (total == 0) {
        if (tid < LSTR_) srow[tid] = 0.0f;   // row 0 zeros (j is always 0)
    } else {
        const int nf4 = T * 32;              // 32 float4s of features per row
        for (int t = tid; t < nf4; t += 256) {
            const int u = t >> 5, q = t & 31;
            const size_t pbase = (size_t)b * N_ + (unsigned)s_idx[u];
            const f4_t v = *(const f4_t*)(feats + pbase * C_ + q * 4);
            #pragma unroll
            for (int jj = 0; jj < 4; ++jj)
                srow[swz(u, 3 + 4 * q + jj)] = v[jj];   // <=2-way: free
        }
        for (int t = tid; t < T * 3; t += 256) {
            const int u = t / 3, k = t - u * 3;
            const size_t pbase = (size_t)b * N_ + (unsigned)s_idx[u];
            srow[swz(u, k)] = points[pbase * 3 + k];
        }
    }
    __syncthreads();

    // --- stream output: 512*131 = 67072 floats = 16768 aligned float4s ---
    float* ob = out + (size_t)bm * (S_ * ROW_);
    if (cnt_eff <= TILE_) {
        // block-uniform fast path: every referenced row is staged
        for (int f = tid; f < (S_ * ROW_) / 4; f += 256) {
            const int e = 4 * f;
            const unsigned s0 = (unsigned)e / (unsigned)ROW_;  // magic-mul
            const int col0 = e - (int)s0 * ROW_;
            const int ja = jtab[s0], jb = jtab[s0 + 1];
            f4_t v;
            #pragma unroll
            for (int jj = 0; jj < 4; ++jj) {
                int col = col0 + jj;
                const bool cross = col >= ROW_;
                col = cross ? col - ROW_ : col;
                const int j = cross ? jb : ja;
                v[jj] = srow[swz(j, col)];   // stride-1 banks: conflict-free
            }
            __builtin_nontemporal_store(v, (f4_t*)(ob + e));
        }
    } else {
        // rare path: some rows not staged -> per-element fallback to global
        for (int f = tid; f < (S_ * ROW_) / 4; f += 256) {
            const int e = 4 * f;
            const unsigned s0 = (unsigned)e / (unsigned)ROW_;
            const int col0 = e - (int)s0 * ROW_;
            f4_t v;
            #pragma unroll
            for (int jj = 0; jj < 4; ++jj) {
                int col = col0 + jj;
                unsigned s = s0;
                if (col >= ROW_) { col -= ROW_; ++s; }
                const int j = jtab[s];
                float val;
                if (j < TILE_) {
                    val = srow[swz(j, col)];
                } else {
                    const size_t pbase = (size_t)b * N_ + (unsigned)s_idx[j];
                    val = (col < 3) ? points[pbase * 3 + col]
                                    : feats[pbase * C_ + (col - 3)];
                }
                v[jj] = val;
            }
            __builtin_nontemporal_store(v, (f4_t*)(ob + e));
        }
    }
    if (tid == 0) flags_out[bm] = (total == 0) ? 1.0f : 0.0f;
}

extern "C" void kernel_launch(void* const* d_in, const int* in_sizes, int n_in,
                              void* d_out, int out_size, void* d_ws, size_t ws_size,
                              hipStream_t stream) {
    const float* points = (const float*)d_in[0];   // (B, N, 3)
    const float* feats  = (const float*)d_in[1];   // (B, N, C)
    const float* boxes  = (const float*)d_in[2];   // (B, M, 7)
    float* out = (float*)d_out;

    // Workspace: masks (1 MB) + cnts (0.5 MB)
    unsigned long long* masks = (unsigned long long*)d_ws;
    int* cnts = (int*)((char*)d_ws + (size_t)B_ * M_ * NCHUNK_ * 8);

    float* flags = out + (size_t)B_ * M_ * S_ * ROW_;

    // Phase A: (512/KBOX_) box-groups x 16 segments = 2048 waves = 512 blocks
    mask_kernel<<<B_ * M_ * 16 / 4 / KBOX_, 256, 0, stream>>>(
        points, boxes, masks, cnts);
    // Fused resolve + pool: one block per box
    pool_kernel<<<B_ * M_, 256, 0, stream>>>(points, feats, masks, cnts, out, flags);
}